// Round 6
// baseline (341.169 us; speedup 1.0000x reference)
//
#include <hip/hip_runtime.h>
#include <hip/hip_bf16.h>

#define N_NODES 50000
#define N_EDGES 800000
#define IN_DIM  256
#define HID     128
#define LEAKY   0.01f

#define H_ELEMS   (N_NODES * IN_DIM)              // 12,800,000
#define W1_ELEMS  (HID * IN_DIM)                  // 32768
#define W2_ELEMS  (HID * HID)                     // 16384
#define PREP_BLOCKS ((H_ELEMS + W1_ELEMS + W2_ELEMS + N_EDGES) / 256)  // 53317 exact

#define EDGE_BLOCKS  ((N_EDGES + 255) / 256)      // 3125
#define NODE_WBLKS   (N_NODES / 4)                // 12500
#define SCAN_BLOCKS  ((N_NODES + 255) / 256)      // 196
#define MTILES       ((N_NODES + 31) / 32)        // 1563 (32-row m-tiles)
#define GEMM_WAVES   (MTILES * 2)                 // 3126 (N-split 2)
#define GEMM_BLOCKS  ((GEMM_WAVES + 3) / 4)       // 782
#define FC1_BLOCKS   (GEMM_BLOCKS + EDGE_BLOCKS)  // 3907 (GEMM + fused fill)

typedef __attribute__((ext_vector_type(8))) short short8;
typedef __attribute__((ext_vector_type(4))) float f32x4;

__device__ __forceinline__ unsigned short f2bf(float x) {
    union { __hip_bfloat16 b; unsigned short u; } c;
    c.b = __float2bfloat16(x);
    return c.u;
}
__device__ __forceinline__ float bf2f(unsigned short u) {
    union { unsigned int u; float f; } c;
    c.u = ((unsigned int)u) << 16;
    return c.f;
}
__device__ __forceinline__ float2 bfu2(unsigned int u) {
    float2 r;
    r.x = bf2f((unsigned short)(u & 0xffff));
    r.y = bf2f((unsigned short)(u >> 16));
    return r;
}
__device__ __forceinline__ float lky(float x) { return x > 0.f ? x : LEAKY * x; }

// -------- prep: h -> bf16 hi/lo planes, W1/W2 splits, dst histogram (all indep) ----

__global__ void prep(const float* __restrict__ h,
                     unsigned short* __restrict__ hhi, unsigned short* __restrict__ hlo,
                     const float* __restrict__ W1, unsigned short* __restrict__ w1hi,
                     unsigned short* __restrict__ w1lo,
                     const float* __restrict__ W2, unsigned short* __restrict__ w2hi,
                     unsigned short* __restrict__ w2lo,
                     const int* __restrict__ dst, int* __restrict__ counts) {
    int i = blockIdx.x * 256 + threadIdx.x;
    if (i < H_ELEMS) {
        float x = h[i];
        unsigned short hb = f2bf(x);
        hhi[i] = hb;
        hlo[i] = f2bf(x - bf2f(hb));
        return;
    }
    int j = i - H_ELEMS;
    if (j < W1_ELEMS) {
        float x = W1[j];
        unsigned short hb = f2bf(x);
        w1hi[j] = hb;
        w1lo[j] = f2bf(x - bf2f(hb));
        return;
    }
    j -= W1_ELEMS;
    if (j < W2_ELEMS) {
        float x = W2[j];
        unsigned short hb = f2bf(x);
        w2hi[j] = hb;
        w2lo[j] = f2bf(x - bf2f(hb));
        return;
    }
    j -= W2_ELEMS;
    atomicAdd(&counts[dst[j]], 1);   // j in [0, N_EDGES)
}

__global__ void scan_block(const int* __restrict__ counts, int* __restrict__ offsets,
                           int* __restrict__ bsums) {
    __shared__ int sh[256];
    int tid = threadIdx.x;
    int i = blockIdx.x * 256 + tid;
    int v = (i < N_NODES) ? counts[i] : 0;
    sh[tid] = v;
    __syncthreads();
    for (int o = 1; o < 256; o <<= 1) {
        int t = (tid >= o) ? sh[tid - o] : 0;
        __syncthreads();
        sh[tid] += t;
        __syncthreads();
    }
    if (i < N_NODES) offsets[i] = sh[tid] - v;
    if (tid == 255) bsums[blockIdx.x] = sh[255];
}

__global__ void scan_add(int* __restrict__ offsets, const int* __restrict__ bsums) {
    __shared__ int sh[256];
    int tid = threadIdx.x;
    int b = blockIdx.x;
    sh[tid] = (tid < b) ? bsums[tid] : 0;   // b <= 195 < 256
    __syncthreads();
    for (int o = 128; o > 0; o >>= 1) {
        if (tid < o) sh[tid] += sh[tid + o];
        __syncthreads();
    }
    int base = sh[0];
    int i = b * 256 + tid;
    if (i < N_NODES) offsets[i] += base;
    if (i == N_NODES) offsets[N_NODES] = N_EDGES;
}

// ---------------- GEMM epilogue for one 16-row subtile ----------------
// C/D: col = lane&15, row = (lane>>4)*4 + reg. Partial scores reduce over r
// via shfl_xor, plain store to q-plane sS[q*N + row] (no atomics).

__device__ __forceinline__ void gemm_epilogue(
        const f32x4* acc, int m0, int q, int lane,
        const float* __restrict__ bias, const float* __restrict__ attn,
        unsigned short* __restrict__ Zb, float* __restrict__ sS, float* __restrict__ sD) {
    int r = lane & 15;
    int rowbase = m0 + (lane >> 4) * 4;
    float ps[4] = {0.f, 0.f, 0.f, 0.f};
    float pd[4] = {0.f, 0.f, 0.f, 0.f};
#pragma unroll
    for (int nt = 0; nt < 4; nt++) {
        int n = q * 64 + nt * 16 + r;
        float bn = bias[n];
        float aS = attn[n];
        float aD = attn[HID + n];
#pragma unroll
        for (int reg = 0; reg < 4; reg++) {
            float zv = acc[nt][reg] + bn;
            Zb[(size_t)(rowbase + reg) * HID + n] = f2bf(zv);
            ps[reg] += zv * aS;
            pd[reg] += zv * aD;
        }
    }
#pragma unroll
    for (int o = 1; o < 16; o <<= 1) {
#pragma unroll
        for (int reg = 0; reg < 4; reg++) {
            ps[reg] += __shfl_xor(ps[reg], o, 64);
            pd[reg] += __shfl_xor(pd[reg], o, 64);
        }
    }
    if (r == 0) {
#pragma unroll
        for (int reg = 0; reg < 4; reg++) {
            sS[q * N_NODES + rowbase + reg] = ps[reg];
            sD[q * N_NODES + rowbase + reg] = pd[reg];
        }
    }
}

// ------- FC1 (+fused fill): 32 rows x 64 cols per wave; A pre-split bf16 -------

__launch_bounds__(256)
__global__ void gemm_fc1_fill(const unsigned short* __restrict__ Ahi,
                              const unsigned short* __restrict__ Alo,
                              const unsigned short* __restrict__ Whi,
                              const unsigned short* __restrict__ Wlo,
                              const float* __restrict__ bias,
                              const float* __restrict__ attn,
                              unsigned short* __restrict__ Zb,
                              float* __restrict__ sS, float* __restrict__ sD,
                              const int* __restrict__ dst, const int* __restrict__ src,
                              const int* __restrict__ offsets,
                              int* __restrict__ cursor, int* __restrict__ csr_src) {
    if (blockIdx.x >= GEMM_BLOCKS) {
        // ---- fused CSR fill (independent of GEMM; hides in its stall cycles) ----
        int i = (blockIdx.x - GEMM_BLOCKS) * 256 + threadIdx.x;
        if (i < N_EDGES) {
            int d = dst[i];
            int p = atomicAdd(&cursor[d], 1);
            csr_src[offsets[d] + p] = src[i];
        }
        return;
    }
    int wave = blockIdx.x * 4 + (threadIdx.x >> 6);
    if (wave >= GEMM_WAVES) return;
    int lane = threadIdx.x & 63;
    int mt = wave >> 1;
    int q  = wave & 1;
    int m0 = mt * 32;
    bool has2 = (m0 + 16 < N_NODES);   // tail tile has only 16 rows
    int r  = lane & 15;
    int ko = (lane >> 4) * 8;

    const unsigned short* A0h = Ahi + (size_t)(m0 + r) * IN_DIM + ko;
    const unsigned short* A0l = Alo + (size_t)(m0 + r) * IN_DIM + ko;
    const unsigned short* A1h = has2 ? (A0h + 16 * IN_DIM) : A0h;
    const unsigned short* A1l = has2 ? (A0l + 16 * IN_DIM) : A0l;
    const unsigned short* Wh = Whi + (size_t)(q * 64 + r) * IN_DIM + ko;
    const unsigned short* Wl = Wlo + (size_t)(q * 64 + r) * IN_DIM + ko;

    f32x4 acc0[4], acc1[4];
#pragma unroll
    for (int i = 0; i < 4; i++) {
        acc0[i] = (f32x4){0.f, 0.f, 0.f, 0.f};
        acc1[i] = (f32x4){0.f, 0.f, 0.f, 0.f};
    }

    short8 a0h = *(const short8*)(A0h);
    short8 a0l = *(const short8*)(A0l);
    short8 a1h = *(const short8*)(A1h);
    short8 a1l = *(const short8*)(A1l);

#pragma unroll
    for (int kt = 0; kt < IN_DIM / 32; kt++) {
        short8 n0h, n0l, n1h, n1l;
        if (kt < IN_DIM / 32 - 1) {
            n0h = *(const short8*)(A0h + (kt + 1) * 32);
            n0l = *(const short8*)(A0l + (kt + 1) * 32);
            n1h = *(const short8*)(A1h + (kt + 1) * 32);
            n1l = *(const short8*)(A1l + (kt + 1) * 32);
        }
#pragma unroll
        for (int nt = 0; nt < 4; nt++) {
            short8 bhi = *(const short8*)(Wh + (size_t)nt * 16 * IN_DIM + kt * 32);
            short8 blo = *(const short8*)(Wl + (size_t)nt * 16 * IN_DIM + kt * 32);
            acc0[nt] = __builtin_amdgcn_mfma_f32_16x16x32_bf16(a0h, bhi, acc0[nt], 0, 0, 0);
            acc0[nt] = __builtin_amdgcn_mfma_f32_16x16x32_bf16(a0l, bhi, acc0[nt], 0, 0, 0);
            acc0[nt] = __builtin_amdgcn_mfma_f32_16x16x32_bf16(a0h, blo, acc0[nt], 0, 0, 0);
            acc1[nt] = __builtin_amdgcn_mfma_f32_16x16x32_bf16(a1h, bhi, acc1[nt], 0, 0, 0);
            acc1[nt] = __builtin_amdgcn_mfma_f32_16x16x32_bf16(a1l, bhi, acc1[nt], 0, 0, 0);
            acc1[nt] = __builtin_amdgcn_mfma_f32_16x16x32_bf16(a1h, blo, acc1[nt], 0, 0, 0);
        }
        if (kt < IN_DIM / 32 - 1) { a0h = n0h; a0l = n0l; a1h = n1h; a1l = n1l; }
    }
    gemm_epilogue(acc0, m0, q, lane, bias, attn, Zb, sS, sD);
    if (has2) gemm_epilogue(acc1, m0 + 16, q, lane, bias, attn, Zb, sS, sD);
}

// ---------------- FC2: 32 rows x 64 cols per wave; A bf16 (h1) ----------------

__launch_bounds__(256)
__global__ void gemm_fc2(const unsigned short* __restrict__ Abf,
                         const unsigned short* __restrict__ Whi,
                         const unsigned short* __restrict__ Wlo,
                         const float* __restrict__ bias,
                         const float* __restrict__ attn,
                         unsigned short* __restrict__ Zb,
                         float* __restrict__ sS, float* __restrict__ sD) {
    int wave = blockIdx.x * 4 + (threadIdx.x >> 6);
    if (wave >= GEMM_WAVES) return;
    int lane = threadIdx.x & 63;
    int mt = wave >> 1;
    int q  = wave & 1;
    int m0 = mt * 32;
    bool has2 = (m0 + 16 < N_NODES);
    int r  = lane & 15;
    int ko = (lane >> 4) * 8;

    const unsigned short* Ap0 = Abf + (size_t)(m0 + r) * HID + ko;
    const unsigned short* Ap1 = has2 ? (Ap0 + 16 * HID) : Ap0;
    const unsigned short* Wh = Whi + (size_t)(q * 64 + r) * HID + ko;
    const unsigned short* Wl = Wlo + (size_t)(q * 64 + r) * HID + ko;

    f32x4 acc0[4], acc1[4];
#pragma unroll
    for (int i = 0; i < 4; i++) {
        acc0[i] = (f32x4){0.f, 0.f, 0.f, 0.f};
        acc1[i] = (f32x4){0.f, 0.f, 0.f, 0.f};
    }

    short8 a0 = *(const short8*)(Ap0);
    short8 a1 = *(const short8*)(Ap1);

#pragma unroll
    for (int kt = 0; kt < HID / 32; kt++) {
        short8 na0, na1;
        if (kt < HID / 32 - 1) {
            na0 = *(const short8*)(Ap0 + (kt + 1) * 32);
            na1 = *(const short8*)(Ap1 + (kt + 1) * 32);
        }
#pragma unroll
        for (int nt = 0; nt < 4; nt++) {
            short8 bhi = *(const short8*)(Wh + (size_t)nt * 16 * HID + kt * 32);
            short8 blo = *(const short8*)(Wl + (size_t)nt * 16 * HID + kt * 32);
            acc0[nt] = __builtin_amdgcn_mfma_f32_16x16x32_bf16(a0, bhi, acc0[nt], 0, 0, 0);
            acc0[nt] = __builtin_amdgcn_mfma_f32_16x16x32_bf16(a0, blo, acc0[nt], 0, 0, 0);
            acc1[nt] = __builtin_amdgcn_mfma_f32_16x16x32_bf16(a1, bhi, acc1[nt], 0, 0, 0);
            acc1[nt] = __builtin_amdgcn_mfma_f32_16x16x32_bf16(a1, blo, acc1[nt], 0, 0, 0);
        }
        if (kt < HID / 32 - 1) { a0 = na0; a1 = na1; }
    }
    gemm_epilogue(acc0, m0, q, lane, bias, attn, Zb, sS, sD);
    if (has2) gemm_epilogue(acc1, m0 + 16, q, lane, bias, attn, Zb, sS, sD);
}

// ---------------- segment softmax + weighted gather-sum + ELU ----------------

template <int OUT_BF>
__launch_bounds__(256)
__global__ void aggregate(const unsigned short* __restrict__ Zb,
                          const int* __restrict__ csr_src,
                          const int* __restrict__ offsets,
                          const float* __restrict__ sS,
                          const float* __restrict__ sD,
                          const float* __restrict__ ab,
                          unsigned short* __restrict__ OutBf,
                          float* __restrict__ OutF) {
    int v = blockIdx.x * 4 + (threadIdx.x >> 6);
    int lane = threadIdx.x & 63;
    int off = offsets[v];
    int deg = offsets[v + 1] - off;
    float sdv = sD[v] + sD[v + N_NODES] + ab[0];

    const unsigned int* Zrow = (const unsigned int*)Zb;  // dword = 2 bf16 dims
    float2 acc = {0.f, 0.f};

    if (deg <= 64) {
        // ---- fast path: per-edge alpha in lane registers, shfl broadcast ----
        bool act = lane < deg;
        int s_l = 0;
        float x = -3.0e38f;
        if (act) {
            s_l = csr_src[off + lane];
            x = lky(sS[s_l] + sS[s_l + N_NODES] + sdv);
        }
        float mx = x;
#pragma unroll
        for (int o = 32; o > 0; o >>= 1) mx = fmaxf(mx, __shfl_xor(mx, o, 64));
        float ex = act ? __expf(x - mx) : 0.f;
        float sum = ex;
#pragma unroll
        for (int o = 32; o > 0; o >>= 1) sum += __shfl_xor(sum, o, 64);
        float al_l = (deg > 0) ? ex / sum : 0.f;

        int t = 0;
        for (; t + 8 <= deg; t += 8) {
            int   s[8];
            float a[8];
            unsigned int rw[8];
#pragma unroll
            for (int j = 0; j < 8; j++) {
                s[j] = __shfl(s_l, t + j, 64);
                a[j] = __shfl(al_l, t + j, 64);
            }
#pragma unroll
            for (int j = 0; j < 8; j++)
                rw[j] = Zrow[(size_t)s[j] * (HID / 2) + lane];
#pragma unroll
            for (int j = 0; j < 8; j++) {
                float2 zz = bfu2(rw[j]);
                acc.x += a[j] * zz.x;
                acc.y += a[j] * zz.y;
            }
        }
        for (; t < deg; t++) {
            int sj = __shfl(s_l, t, 64);
            float aj = __shfl(al_l, t, 64);
            float2 zz = bfu2(Zrow[(size_t)sj * (HID / 2) + lane]);
            acc.x += aj * zz.x;
            acc.y += aj * zz.y;
        }
    } else {
        // ---- slow path (deg > 64) ----
        float mx = -3.0e38f;
        for (int t = lane; t < deg; t += 64) {
            int s = csr_src[off + t];
            mx = fmaxf(mx, lky(sS[s] + sS[s + N_NODES] + sdv));
        }
#pragma unroll
        for (int o = 32; o > 0; o >>= 1) mx = fmaxf(mx, __shfl_xor(mx, o, 64));
        float sum = 0.f;
        for (int t = lane; t < deg; t += 64) {
            int s = csr_src[off + t];
            sum += __expf(lky(sS[s] + sS[s + N_NODES] + sdv) - mx);
        }
#pragma unroll
        for (int o = 32; o > 0; o >>= 1) sum += __shfl_xor(sum, o, 64);
        float inv = 1.f / sum;
        for (int t = 0; t < deg; t++) {
            int s = csr_src[off + t];
            float al = __expf(lky(sS[s] + sS[s + N_NODES] + sdv) - mx) * inv;
            float2 zz = bfu2(Zrow[(size_t)s * (HID / 2) + lane]);
            acc.x += al * zz.x;
            acc.y += al * zz.y;
        }
    }

    // ELU
    acc.x = acc.x > 0.f ? acc.x : __expf(acc.x) - 1.f;
    acc.y = acc.y > 0.f ? acc.y : __expf(acc.y) - 1.f;

    if (OUT_BF) {
        ushort2 o2;
        o2.x = f2bf(acc.x);
        o2.y = f2bf(acc.y);
        *((ushort2*)(OutBf + (size_t)v * HID + lane * 2)) = o2;
    } else {
        float2 o2 = {acc.x, acc.y};
        *((float2*)(OutF + (size_t)v * HID + lane * 2)) = o2;
    }
}

// ---------------- launch ----------------

extern "C" void kernel_launch(void* const* d_in, const int* in_sizes, int n_in,
                              void* d_out, int out_size, void* d_ws, size_t ws_size,
                              hipStream_t stream) {
    const float* h   = (const float*)d_in[0];
    const int*   src = (const int*)d_in[1];
    const int*   dst = (const int*)d_in[2];
    const float* W1  = (const float*)d_in[3];
    const float* b1  = (const float*)d_in[4];
    const float* a1  = (const float*)d_in[5];
    const float* ab1 = (const float*)d_in[6];
    const float* W2  = (const float*)d_in[7];
    const float* b2  = (const float*)d_in[8];
    const float* a2  = (const float*)d_in[9];
    const float* ab2 = (const float*)d_in[10];
    float* out = (float*)d_out;

    // workspace carve-up (~82 MB)
    unsigned short* zb = (unsigned short*)d_ws;                 // 50000*128 bf16
    float* sS = (float*)(zb + (size_t)N_NODES * HID);           // 2*50000 f32 (q-planes)
    float* sD = sS + 2 * N_NODES;                               // 2*50000 f32
    int* counts  = (int*)(sD + 2 * N_NODES);                    // 50000
    int* cursor  = counts + N_NODES;                            // 50000 (contiguous)
    int* offsets = cursor + N_NODES;                            // 50001 (+pad)
    int* bsums   = offsets + N_NODES + 16;                      // 256
    unsigned short* h1   = (unsigned short*)(bsums + 256);      // 50000*128 bf16
    unsigned short* w1hi = h1 + (size_t)N_NODES * HID;          // 32768
    unsigned short* w1lo = w1hi + W1_ELEMS;
    unsigned short* w2hi = w1lo + W1_ELEMS;                     // 16384
    unsigned short* w2lo = w2hi + W2_ELEMS;
    int* csr_src = (int*)(w2lo + W2_ELEMS);                     // 800000
    unsigned short* hhi = (unsigned short*)(csr_src + N_EDGES); // 12.8M bf16
    unsigned short* hlo = hhi + (size_t)H_ELEMS;                // 12.8M bf16

    // zero counts + cursor (contiguous)
    hipMemsetAsync(counts, 0, 2 * (size_t)N_NODES * sizeof(int), stream);

    // prep: h hi/lo planes + W splits + dst histogram (one fat dispatch)
    prep<<<PREP_BLOCKS, 256, 0, stream>>>(h, hhi, hlo, W1, w1hi, w1lo,
                                          W2, w2hi, w2lo, dst, counts);
    scan_block<<<SCAN_BLOCKS, 256, 0, stream>>>(counts, offsets, bsums);
    scan_add<<<SCAN_BLOCKS, 256, 0, stream>>>(offsets, bsums);

    // layer 1 GEMM + fused CSR fill
    gemm_fc1_fill<<<FC1_BLOCKS, 256, 0, stream>>>(hhi, hlo, w1hi, w1lo, b1, a1,
                                                  zb, sS, sD,
                                                  dst, src, offsets, cursor, csr_src);
    aggregate<1><<<NODE_WBLKS, 256, 0, stream>>>(zb, csr_src, offsets, sS, sD, ab1, h1, nullptr);

    // layer 2
    gemm_fc2<<<GEMM_BLOCKS, 256, 0, stream>>>(h1, w2hi, w2lo, b2, a2, zb, sS, sD);
    aggregate<0><<<NODE_WBLKS, 256, 0, stream>>>(zb, csr_src, offsets, sS, sD, ab2, nullptr, out);
}

// Round 7
// 303.721 us; speedup vs baseline: 1.1233x; 1.1233x over previous
//
#include <hip/hip_runtime.h>
#include <hip/hip_bf16.h>

#define N_NODES 50000
#define N_EDGES 800000
#define IN_DIM  256
#define HID     128
#define LEAKY   0.01f

#define EDGE_BLOCKS  ((N_EDGES + 255) / 256)      // 3125
#define NODE_WBLKS   (N_NODES / 4)                // 12500
#define SCAN_BLOCKS  ((N_NODES + 255) / 256)      // 196
#define W1_ELEMS  (HID * IN_DIM)                  // 32768
#define W2_ELEMS  (HID * HID)                     // 16384

#define TM        96                              // GEMM rows per block
#define FC_BLOCKS ((N_NODES + TM - 1) / TM)       // 521
#define LDA       72                              // LDS row stride (shorts), 144B (16B-mult, bank-spread)

typedef __attribute__((ext_vector_type(8))) short short8;
typedef __attribute__((ext_vector_type(4))) float f32x4;

__device__ __forceinline__ unsigned short f2bf(float x) {
    union { __hip_bfloat16 b; unsigned short u; } c;
    c.b = __float2bfloat16(x);
    return c.u;
}
__device__ __forceinline__ float bf2f(unsigned short u) {
    union { unsigned int u; float f; } c;
    c.u = ((unsigned int)u) << 16;
    return c.f;
}
__device__ __forceinline__ float2 bfu2(unsigned int u) {
    float2 r;
    r.x = bf2f((unsigned short)(u & 0xffff));
    r.y = bf2f((unsigned short)(u >> 16));
    return r;
}
__device__ __forceinline__ float lky(float x) { return x > 0.f ? x : LEAKY * x; }

// ---------------- CSR hist + W splits (fused, independent work) ----------------

__global__ void hist_split(const int* __restrict__ dst, int* __restrict__ counts,
                           const float* __restrict__ W1, unsigned short* __restrict__ w1hi,
                           unsigned short* __restrict__ w1lo,
                           const float* __restrict__ W2, unsigned short* __restrict__ w2hi,
                           unsigned short* __restrict__ w2lo) {
    int i = blockIdx.x * 256 + threadIdx.x;
    if (i < N_EDGES) atomicAdd(&counts[dst[i]], 1);
    if (i < W1_ELEMS) {
        float x = W1[i];
        unsigned short h = f2bf(x);
        w1hi[i] = h;
        w1lo[i] = f2bf(x - bf2f(h));
    } else if (i < W1_ELEMS + W2_ELEMS) {
        int j = i - W1_ELEMS;
        float x = W2[j];
        unsigned short h = f2bf(x);
        w2hi[j] = h;
        w2lo[j] = f2bf(x - bf2f(h));
    }
}

__global__ void scan_block(const int* __restrict__ counts, int* __restrict__ offsets,
                           int* __restrict__ bsums) {
    __shared__ int sh[256];
    int tid = threadIdx.x;
    int i = blockIdx.x * 256 + tid;
    int v = (i < N_NODES) ? counts[i] : 0;
    sh[tid] = v;
    __syncthreads();
    for (int o = 1; o < 256; o <<= 1) {
        int t = (tid >= o) ? sh[tid - o] : 0;
        __syncthreads();
        sh[tid] += t;
        __syncthreads();
    }
    if (i < N_NODES) offsets[i] = sh[tid] - v;
    if (tid == 255) bsums[blockIdx.x] = sh[255];
}

__global__ void scan_add(int* __restrict__ offsets, const int* __restrict__ bsums) {
    __shared__ int sh[256];
    int tid = threadIdx.x;
    int b = blockIdx.x;
    sh[tid] = (tid < b) ? bsums[tid] : 0;   // b <= 195 < 256
    __syncthreads();
    for (int o = 128; o > 0; o >>= 1) {
        if (tid < o) sh[tid] += sh[tid + o];
        __syncthreads();
    }
    int base = sh[0];
    int i = b * 256 + tid;
    if (i < N_NODES) offsets[i] += base;
    if (i == N_NODES) offsets[N_NODES] = N_EDGES;
}

__global__ void fill_kernel(const int* __restrict__ dst, const int* __restrict__ src,
                            const int* __restrict__ offsets,
                            int* __restrict__ cursor, int* __restrict__ csr_src) {
    int i = blockIdx.x * 256 + threadIdx.x;
    if (i < N_EDGES) {
        int d = dst[i];
        int p = atomicAdd(&cursor[d], 1);
        csr_src[offsets[d] + p] = src[i];
    }
}

// ---------------- epilogue for one 16-row subtile (4 nt accs, 64-col slice) -----
// C/D: col = lane&15, row = (lane>>4)*4 + reg. Scores reduce over r via
// shfl_xor, plain store to q-plane sS[q*N + row].

__device__ __forceinline__ void epi(const f32x4* accn, int mbase, int q, int lane,
                                    const float* __restrict__ bias,
                                    const float* __restrict__ attn,
                                    unsigned short* __restrict__ Zb,
                                    float* __restrict__ sS, float* __restrict__ sD) {
    int r = lane & 15;
    int rowbase = mbase + (lane >> 4) * 4;
    float ps[4] = {0.f, 0.f, 0.f, 0.f};
    float pd[4] = {0.f, 0.f, 0.f, 0.f};
#pragma unroll
    for (int nt = 0; nt < 4; nt++) {
        int n = q * 64 + nt * 16 + r;
        float bn = bias[n];
        float aS = attn[n];
        float aD = attn[HID + n];
#pragma unroll
        for (int reg = 0; reg < 4; reg++) {
            float zv = accn[nt][reg] + bn;
            if (rowbase + reg < N_NODES)
                Zb[(size_t)(rowbase + reg) * HID + n] = f2bf(zv);
            ps[reg] += zv * aS;
            pd[reg] += zv * aD;
        }
    }
#pragma unroll
    for (int o = 1; o < 16; o <<= 1) {
#pragma unroll
        for (int reg = 0; reg < 4; reg++) {
            ps[reg] += __shfl_xor(ps[reg], o, 64);
            pd[reg] += __shfl_xor(pd[reg], o, 64);
        }
    }
    if (r == 0) {
#pragma unroll
        for (int reg = 0; reg < 4; reg++) {
            if (rowbase + reg < N_NODES) {
                sS[q * N_NODES + rowbase + reg] = ps[reg];
                sD[q * N_NODES + rowbase + reg] = pd[reg];
            }
        }
    }
}

// ------- FC1: LDS-tiled. Block = 96 rows x 128 cols, K in 64-elem chunks. -------
// A fp32 staged+repacked to hi/lo bf16 LDS planes; W pre-split planes staged.
// Wave w: q = w&1 (64-col half), mh = w>>1 (48-row half), 3 subtiles x 4 nt.

__launch_bounds__(256)
__global__ void gemm_fc1(const float* __restrict__ A,
                         const unsigned short* __restrict__ Whi,
                         const unsigned short* __restrict__ Wlo,
                         const float* __restrict__ bias,
                         const float* __restrict__ attn,
                         unsigned short* __restrict__ Zb,
                         float* __restrict__ sS, float* __restrict__ sD) {
    __shared__ unsigned short Ah[TM * LDA];   // 13824 B
    __shared__ unsigned short Al[TM * LDA];   // 13824 B
    __shared__ unsigned short Bh[HID * LDA];  // 18432 B
    __shared__ unsigned short Bl[HID * LDA];  // 18432 B  (total 64512 B)

    int tid  = threadIdx.x;
    int lane = tid & 63;
    int w    = tid >> 6;
    int q    = w & 1;
    int mh   = w >> 1;
    int m0   = blockIdx.x * TM;
    int r    = lane & 15;
    int koff = (lane >> 4) * 8;

    f32x4 acc[3][4];
#pragma unroll
    for (int s = 0; s < 3; s++)
#pragma unroll
        for (int nt = 0; nt < 4; nt++) acc[s][nt] = (f32x4){0.f, 0.f, 0.f, 0.f};

    for (int kc = 0; kc < IN_DIM / 64; kc++) {
        int k0 = kc * 64;
        __syncthreads();
        // stage A: 96 rows x 64 fp32 (24 KB) -> hi/lo bf16 planes; 6 x 16B/thread
#pragma unroll
        for (int j = 0; j < 6; j++) {
            int flat = j * 256 + tid;
            int row = flat >> 4;
            int c4 = (flat & 15) << 2;
            int gr = m0 + row;
            if (gr >= N_NODES) gr = N_NODES - 1;
            float4 v = *(const float4*)(A + (size_t)gr * IN_DIM + k0 + c4);
            unsigned short h0 = f2bf(v.x), h1 = f2bf(v.y), h2 = f2bf(v.z), h3 = f2bf(v.w);
            short4 hv = {(short)h0, (short)h1, (short)h2, (short)h3};
            short4 lv = {(short)f2bf(v.x - bf2f(h0)), (short)f2bf(v.y - bf2f(h1)),
                         (short)f2bf(v.z - bf2f(h2)), (short)f2bf(v.w - bf2f(h3))};
            *(short4*)&Ah[row * LDA + c4] = hv;
            *(short4*)&Al[row * LDA + c4] = lv;
        }
        // stage W hi/lo: 128 n x 64 halves each (16 KB); 4 x 16B/thread per plane
#pragma unroll
        for (int j = 0; j < 4; j++) {
            int flat = j * 256 + tid;
            int n = flat >> 3;
            int c8 = (flat & 7) << 3;
            *(short8*)&Bh[n * LDA + c8] = *(const short8*)(Whi + (size_t)n * IN_DIM + k0 + c8);
            *(short8*)&Bl[n * LDA + c8] = *(const short8*)(Wlo + (size_t)n * IN_DIM + k0 + c8);
        }
        __syncthreads();
        // compute: 2 k-steps of 32
#pragma unroll
        for (int ks = 0; ks < 2; ks++) {
            int kk = ks * 32 + koff;
            short8 ah[3], al[3], bh[4], bl[4];
#pragma unroll
            for (int s = 0; s < 3; s++) {
                int row = mh * 48 + s * 16 + r;
                ah[s] = *(const short8*)&Ah[row * LDA + kk];
                al[s] = *(const short8*)&Al[row * LDA + kk];
            }
#pragma unroll
            for (int nt = 0; nt < 4; nt++) {
                int n = q * 64 + nt * 16 + r;
                bh[nt] = *(const short8*)&Bh[n * LDA + kk];
                bl[nt] = *(const short8*)&Bl[n * LDA + kk];
            }
#pragma unroll
            for (int s = 0; s < 3; s++)
#pragma unroll
                for (int nt = 0; nt < 4; nt++) {
                    acc[s][nt] = __builtin_amdgcn_mfma_f32_16x16x32_bf16(ah[s], bh[nt], acc[s][nt], 0, 0, 0);
                    acc[s][nt] = __builtin_amdgcn_mfma_f32_16x16x32_bf16(al[s], bh[nt], acc[s][nt], 0, 0, 0);
                    acc[s][nt] = __builtin_amdgcn_mfma_f32_16x16x32_bf16(ah[s], bl[nt], acc[s][nt], 0, 0, 0);
                }
        }
    }
#pragma unroll
    for (int s = 0; s < 3; s++)
        epi(acc[s], m0 + mh * 48 + s * 16, q, lane, bias, attn, Zb, sS, sD);
}

// ------- FC2: LDS-tiled. A = h1 (single bf16 plane), W2 hi/lo. K=128, 2 chunks. ----

__launch_bounds__(256)
__global__ void gemm_fc2(const unsigned short* __restrict__ Abf,
                         const unsigned short* __restrict__ Whi,
                         const unsigned short* __restrict__ Wlo,
                         const float* __restrict__ bias,
                         const float* __restrict__ attn,
                         unsigned short* __restrict__ Zb,
                         float* __restrict__ sS, float* __restrict__ sD) {
    __shared__ unsigned short Ah[TM * LDA];   // 13824 B
    __shared__ unsigned short Bh[HID * LDA];  // 18432 B
    __shared__ unsigned short Bl[HID * LDA];  // 18432 B  (total 50688 B)

    int tid  = threadIdx.x;
    int lane = tid & 63;
    int w    = tid >> 6;
    int q    = w & 1;
    int mh   = w >> 1;
    int m0   = blockIdx.x * TM;
    int r    = lane & 15;
    int koff = (lane >> 4) * 8;

    f32x4 acc[3][4];
#pragma unroll
    for (int s = 0; s < 3; s++)
#pragma unroll
        for (int nt = 0; nt < 4; nt++) acc[s][nt] = (f32x4){0.f, 0.f, 0.f, 0.f};

    for (int kc = 0; kc < HID / 64; kc++) {
        int k0 = kc * 64;
        __syncthreads();
        // stage A: 96 rows x 64 bf16 (12 KB); 3 x 16B/thread
#pragma unroll
        for (int j = 0; j < 3; j++) {
            int flat = j * 256 + tid;
            int row = flat >> 3;
            int c8 = (flat & 7) << 3;
            int gr = m0 + row;
            if (gr >= N_NODES) gr = N_NODES - 1;
            *(short8*)&Ah[row * LDA + c8] = *(const short8*)(Abf + (size_t)gr * HID + k0 + c8);
        }
        // stage W2 hi/lo
#pragma unroll
        for (int j = 0; j < 4; j++) {
            int flat = j * 256 + tid;
            int n = flat >> 3;
            int c8 = (flat & 7) << 3;
            *(short8*)&Bh[n * LDA + c8] = *(const short8*)(Whi + (size_t)n * HID + k0 + c8);
            *(short8*)&Bl[n * LDA + c8] = *(const short8*)(Wlo + (size_t)n * HID + k0 + c8);
        }
        __syncthreads();
#pragma unroll
        for (int ks = 0; ks < 2; ks++) {
            int kk = ks * 32 + koff;
            short8 ah[3], bh[4], bl[4];
#pragma unroll
            for (int s = 0; s < 3; s++) {
                int row = mh * 48 + s * 16 + r;
                ah[s] = *(const short8*)&Ah[row * LDA + kk];
            }
#pragma unroll
            for (int nt = 0; nt < 4; nt++) {
                int n = q * 64 + nt * 16 + r;
                bh[nt] = *(const short8*)&Bh[n * LDA + kk];
                bl[nt] = *(const short8*)&Bl[n * LDA + kk];
            }
#pragma unroll
            for (int s = 0; s < 3; s++)
#pragma unroll
                for (int nt = 0; nt < 4; nt++) {
                    acc[s][nt] = __builtin_amdgcn_mfma_f32_16x16x32_bf16(ah[s], bh[nt], acc[s][nt], 0, 0, 0);
                    acc[s][nt] = __builtin_amdgcn_mfma_f32_16x16x32_bf16(ah[s], bl[nt], acc[s][nt], 0, 0, 0);
                }
        }
    }
#pragma unroll
    for (int s = 0; s < 3; s++)
        epi(acc[s], m0 + mh * 48 + s * 16, q, lane, bias, attn, Zb, sS, sD);
}

// ---------------- segment softmax + weighted gather-sum + ELU ----------------

template <int OUT_BF>
__launch_bounds__(256)
__global__ void aggregate(const unsigned short* __restrict__ Zb,
                          const int* __restrict__ csr_src,
                          const int* __restrict__ offsets,
                          const float* __restrict__ sS,
                          const float* __restrict__ sD,
                          const float* __restrict__ ab,
                          unsigned short* __restrict__ OutBf,
                          float* __restrict__ OutF) {
    int v = blockIdx.x * 4 + (threadIdx.x >> 6);
    int lane = threadIdx.x & 63;
    int off = offsets[v];
    int deg = offsets[v + 1] - off;
    float sdv = sD[v] + sD[v + N_NODES] + ab[0];

    const unsigned int* Zrow = (const unsigned int*)Zb;  // dword = 2 bf16 dims
    float2 acc = {0.f, 0.f};

    if (deg <= 64) {
        bool act = lane < deg;
        int s_l = 0;
        float x = -3.0e38f;
        if (act) {
            s_l = csr_src[off + lane];
            x = lky(sS[s_l] + sS[s_l + N_NODES] + sdv);
        }
        float mx = x;
#pragma unroll
        for (int o = 32; o > 0; o >>= 1) mx = fmaxf(mx, __shfl_xor(mx, o, 64));
        float ex = act ? __expf(x - mx) : 0.f;
        float sum = ex;
#pragma unroll
        for (int o = 32; o > 0; o >>= 1) sum += __shfl_xor(sum, o, 64);
        float al_l = (deg > 0) ? ex / sum : 0.f;

        int t = 0;
        for (; t + 8 <= deg; t += 8) {
            int   s[8];
            float a[8];
            unsigned int rw[8];
#pragma unroll
            for (int j = 0; j < 8; j++) {
                s[j] = __shfl(s_l, t + j, 64);
                a[j] = __shfl(al_l, t + j, 64);
            }
#pragma unroll
            for (int j = 0; j < 8; j++)
                rw[j] = Zrow[(size_t)s[j] * (HID / 2) + lane];
#pragma unroll
            for (int j = 0; j < 8; j++) {
                float2 zz = bfu2(rw[j]);
                acc.x += a[j] * zz.x;
                acc.y += a[j] * zz.y;
            }
        }
        for (; t < deg; t++) {
            int sj = __shfl(s_l, t, 64);
            float aj = __shfl(al_l, t, 64);
            float2 zz = bfu2(Zrow[(size_t)sj * (HID / 2) + lane]);
            acc.x += aj * zz.x;
            acc.y += aj * zz.y;
        }
    } else {
        float mx = -3.0e38f;
        for (int t = lane; t < deg; t += 64) {
            int s = csr_src[off + t];
            mx = fmaxf(mx, lky(sS[s] + sS[s + N_NODES] + sdv));
        }
#pragma unroll
        for (int o = 32; o > 0; o >>= 1) mx = fmaxf(mx, __shfl_xor(mx, o, 64));
        float sum = 0.f;
        for (int t = lane; t < deg; t += 64) {
            int s = csr_src[off + t];
            sum += __expf(lky(sS[s] + sS[s + N_NODES] + sdv) - mx);
        }
#pragma unroll
        for (int o = 32; o > 0; o >>= 1) sum += __shfl_xor(sum, o, 64);
        float inv = 1.f / sum;
        for (int t = 0; t < deg; t++) {
            int s = csr_src[off + t];
            float al = __expf(lky(sS[s] + sS[s + N_NODES] + sdv) - mx) * inv;
            float2 zz = bfu2(Zrow[(size_t)s * (HID / 2) + lane]);
            acc.x += al * zz.x;
            acc.y += al * zz.y;
        }
    }

    acc.x = acc.x > 0.f ? acc.x : __expf(acc.x) - 1.f;
    acc.y = acc.y > 0.f ? acc.y : __expf(acc.y) - 1.f;

    if (OUT_BF) {
        ushort2 o2;
        o2.x = f2bf(acc.x);
        o2.y = f2bf(acc.y);
        *((ushort2*)(OutBf + (size_t)v * HID + lane * 2)) = o2;
    } else {
        float2 o2 = {acc.x, acc.y};
        *((float2*)(OutF + (size_t)v * HID + lane * 2)) = o2;
    }
}

// ---------------- launch ----------------

extern "C" void kernel_launch(void* const* d_in, const int* in_sizes, int n_in,
                              void* d_out, int out_size, void* d_ws, size_t ws_size,
                              hipStream_t stream) {
    const float* h   = (const float*)d_in[0];
    const int*   src = (const int*)d_in[1];
    const int*   dst = (const int*)d_in[2];
    const float* W1  = (const float*)d_in[3];
    const float* b1  = (const float*)d_in[4];
    const float* a1  = (const float*)d_in[5];
    const float* ab1 = (const float*)d_in[6];
    const float* W2  = (const float*)d_in[7];
    const float* b2  = (const float*)d_in[8];
    const float* a2  = (const float*)d_in[9];
    const float* ab2 = (const float*)d_in[10];
    float* out = (float*)d_out;

    // workspace carve-up (~31 MB)
    unsigned short* zb = (unsigned short*)d_ws;                 // 50000*128 bf16
    float* sS = (float*)(zb + (size_t)N_NODES * HID);           // 2*50000 f32 (q-planes)
    float* sD = sS + 2 * N_NODES;                               // 2*50000 f32
    int* counts  = (int*)(sD + 2 * N_NODES);                    // 50000
    int* cursor  = counts + N_NODES;                            // 50000 (contiguous)
    int* offsets = cursor + N_NODES;                            // 50001 (+pad)
    int* bsums   = offsets + N_NODES + 16;                      // 256
    unsigned short* h1   = (unsigned short*)(bsums + 256);      // 50000*128 bf16
    unsigned short* w1hi = h1 + (size_t)N_NODES * HID;          // 32768
    unsigned short* w1lo = w1hi + W1_ELEMS;
    unsigned short* w2hi = w1lo + W1_ELEMS;                     // 16384
    unsigned short* w2lo = w2hi + W2_ELEMS;
    int* csr_src = (int*)(w2lo + W2_ELEMS);                     // 800000

    hipMemsetAsync(counts, 0, 2 * (size_t)N_NODES * sizeof(int), stream);

    // CSR by dst + weight splits
    hist_split<<<EDGE_BLOCKS, 256, 0, stream>>>(dst, counts, W1, w1hi, w1lo, W2, w2hi, w2lo);
    scan_block<<<SCAN_BLOCKS, 256, 0, stream>>>(counts, offsets, bsums);
    scan_add<<<SCAN_BLOCKS, 256, 0, stream>>>(offsets, bsums);
    fill_kernel<<<EDGE_BLOCKS, 256, 0, stream>>>(dst, src, offsets, cursor, csr_src);

    // layer 1
    gemm_fc1<<<FC_BLOCKS, 256, 0, stream>>>(h, w1hi, w1lo, b1, a1, zb, sS, sD);
    aggregate<1><<<NODE_WBLKS, 256, 0, stream>>>(zb, csr_src, offsets, sS, sD, ab1, h1, nullptr);

    // layer 2
    gemm_fc2<<<FC_BLOCKS, 256, 0, stream>>>(h1, w2hi, w2lo, b2, a2, zb, sS, sD);
    aggregate<0><<<NODE_WBLKS, 256, 0, stream>>>(zb, csr_src, offsets, sS, sD, ab2, nullptr, out);
}

// Round 8
// 290.159 us; speedup vs baseline: 1.1758x; 1.0467x over previous
//
#include <hip/hip_runtime.h>
#include <hip/hip_bf16.h>

#define N_NODES 50000
#define N_EDGES 800000
#define IN_DIM  256
#define HID     128
#define LEAKY   0.01f

#define EDGE_BLOCKS  ((N_EDGES + 255) / 256)      // 3125
#define NODE_WBLKS   (N_NODES / 4)                // 12500
#define SCAN_BLOCKS  ((N_NODES + 255) / 256)      // 196
#define W1_ELEMS  (HID * IN_DIM)                  // 32768
#define W2_ELEMS  (HID * HID)                     // 16384

#define TM        96                              // GEMM rows per block
#define FC_BLOCKS ((N_NODES + TM - 1) / TM)       // 521
#define LDA       72                              // LDS row stride (shorts)

typedef __attribute__((ext_vector_type(8))) short short8;
typedef __attribute__((ext_vector_type(4))) float f32x4;

__device__ __forceinline__ unsigned short f2bf(float x) {
    union { __hip_bfloat16 b; unsigned short u; } c;
    c.b = __float2bfloat16(x);
    return c.u;
}
__device__ __forceinline__ float bf2f(unsigned short u) {
    union { unsigned int u; float f; } c;
    c.u = ((unsigned int)u) << 16;
    return c.f;
}
__device__ __forceinline__ float2 bfu2(unsigned int u) {
    float2 r;
    r.x = bf2f((unsigned short)(u & 0xffff));
    r.y = bf2f((unsigned short)(u >> 16));
    return r;
}
__device__ __forceinline__ float lky(float x) { return x > 0.f ? x : LEAKY * x; }

// ------- CSR hist (rank-returning) + W splits (fused, independent work) --------

__global__ void hist_split(const int* __restrict__ dst, int* __restrict__ counts,
                           int* __restrict__ erank,
                           const float* __restrict__ W1, unsigned short* __restrict__ w1hi,
                           unsigned short* __restrict__ w1lo,
                           const float* __restrict__ W2, unsigned short* __restrict__ w2hi,
                           unsigned short* __restrict__ w2lo) {
    int i = blockIdx.x * 256 + threadIdx.x;
    if (i < N_EDGES) erank[i] = atomicAdd(&counts[dst[i]], 1);
    if (i < W1_ELEMS) {
        float x = W1[i];
        unsigned short h = f2bf(x);
        w1hi[i] = h;
        w1lo[i] = f2bf(x - bf2f(h));
    } else if (i < W1_ELEMS + W2_ELEMS) {
        int j = i - W1_ELEMS;
        float x = W2[j];
        unsigned short h = f2bf(x);
        w2hi[j] = h;
        w2lo[j] = f2bf(x - bf2f(h));
    }
}

__global__ void scan_block(const int* __restrict__ counts, int* __restrict__ offsets,
                           int* __restrict__ bsums) {
    __shared__ int sh[256];
    int tid = threadIdx.x;
    int i = blockIdx.x * 256 + tid;
    int v = (i < N_NODES) ? counts[i] : 0;
    sh[tid] = v;
    __syncthreads();
    for (int o = 1; o < 256; o <<= 1) {
        int t = (tid >= o) ? sh[tid - o] : 0;
        __syncthreads();
        sh[tid] += t;
        __syncthreads();
    }
    if (i < N_NODES) offsets[i] = sh[tid] - v;
    if (tid == 255) bsums[blockIdx.x] = sh[255];
}

__global__ void scan_add(int* __restrict__ offsets, const int* __restrict__ bsums) {
    __shared__ int sh[256];
    int tid = threadIdx.x;
    int b = blockIdx.x;
    sh[tid] = (tid < b) ? bsums[tid] : 0;   // b <= 195 < 256
    __syncthreads();
    for (int o = 128; o > 0; o >>= 1) {
        if (tid < o) sh[tid] += sh[tid + o];
        __syncthreads();
    }
    int base = sh[0];
    int i = b * 256 + tid;
    if (i < N_NODES) offsets[i] += base;
    if (i == N_NODES) offsets[N_NODES] = N_EDGES;
}

// fill: atomic-free scatter; nontemporal store to avoid cross-XCD L2 line bounce
__global__ void fill_kernel(const int* __restrict__ dst, const int* __restrict__ src,
                            const int* __restrict__ erank,
                            const int* __restrict__ offsets,
                            int* __restrict__ csr_src) {
    int i = blockIdx.x * 256 + threadIdx.x;
    if (i < N_EDGES) {
        int d = dst[i];
        int slot = offsets[d] + erank[i];
        __builtin_nontemporal_store(src[i], &csr_src[slot]);
    }
}

// ---------------- epilogue for one 16-row subtile (4 nt accs, 64-col slice) -----

__device__ __forceinline__ void epi(const f32x4* accn, int mbase, int q, int lane,
                                    const float* __restrict__ bias,
                                    const float* __restrict__ attn,
                                    unsigned short* __restrict__ Zb,
                                    float* __restrict__ sS, float* __restrict__ sD) {
    int r = lane & 15;
    int rowbase = mbase + (lane >> 4) * 4;
    float ps[4] = {0.f, 0.f, 0.f, 0.f};
    float pd[4] = {0.f, 0.f, 0.f, 0.f};
#pragma unroll
    for (int nt = 0; nt < 4; nt++) {
        int n = q * 64 + nt * 16 + r;
        float bn = bias[n];
        float aS = attn[n];
        float aD = attn[HID + n];
#pragma unroll
        for (int reg = 0; reg < 4; reg++) {
            float zv = accn[nt][reg] + bn;
            if (rowbase + reg < N_NODES)
                Zb[(size_t)(rowbase + reg) * HID + n] = f2bf(zv);
            ps[reg] += zv * aS;
            pd[reg] += zv * aD;
        }
    }
#pragma unroll
    for (int o = 1; o < 16; o <<= 1) {
#pragma unroll
        for (int reg = 0; reg < 4; reg++) {
            ps[reg] += __shfl_xor(ps[reg], o, 64);
            pd[reg] += __shfl_xor(pd[reg], o, 64);
        }
    }
    if (r == 0) {
#pragma unroll
        for (int reg = 0; reg < 4; reg++) {
            if (rowbase + reg < N_NODES) {
                sS[q * N_NODES + rowbase + reg] = ps[reg];
                sD[q * N_NODES + rowbase + reg] = pd[reg];
            }
        }
    }
}

// ------- FC1: LDS-tiled. Block = 96 rows x 128 cols, K in 64-elem chunks. -------

__launch_bounds__(256)
__global__ void gemm_fc1(const float* __restrict__ A,
                         const unsigned short* __restrict__ Whi,
                         const unsigned short* __restrict__ Wlo,
                         const float* __restrict__ bias,
                         const float* __restrict__ attn,
                         unsigned short* __restrict__ Zb,
                         float* __restrict__ sS, float* __restrict__ sD) {
    __shared__ unsigned short Ah[TM * LDA];
    __shared__ unsigned short Al[TM * LDA];
    __shared__ unsigned short Bh[HID * LDA];
    __shared__ unsigned short Bl[HID * LDA];

    int tid  = threadIdx.x;
    int lane = tid & 63;
    int w    = tid >> 6;
    int q    = w & 1;
    int mh   = w >> 1;
    int m0   = blockIdx.x * TM;
    int r    = lane & 15;
    int koff = (lane >> 4) * 8;

    f32x4 acc[3][4];
#pragma unroll
    for (int s = 0; s < 3; s++)
#pragma unroll
        for (int nt = 0; nt < 4; nt++) acc[s][nt] = (f32x4){0.f, 0.f, 0.f, 0.f};

    for (int kc = 0; kc < IN_DIM / 64; kc++) {
        int k0 = kc * 64;
        __syncthreads();
#pragma unroll
        for (int j = 0; j < 6; j++) {
            int flat = j * 256 + tid;
            int row = flat >> 4;
            int c4 = (flat & 15) << 2;
            int gr = m0 + row;
            if (gr >= N_NODES) gr = N_NODES - 1;
            float4 v = *(const float4*)(A + (size_t)gr * IN_DIM + k0 + c4);
            unsigned short h0 = f2bf(v.x), h1 = f2bf(v.y), h2 = f2bf(v.z), h3 = f2bf(v.w);
            short4 hv = {(short)h0, (short)h1, (short)h2, (short)h3};
            short4 lv = {(short)f2bf(v.x - bf2f(h0)), (short)f2bf(v.y - bf2f(h1)),
                         (short)f2bf(v.z - bf2f(h2)), (short)f2bf(v.w - bf2f(h3))};
            *(short4*)&Ah[row * LDA + c4] = hv;
            *(short4*)&Al[row * LDA + c4] = lv;
        }
#pragma unroll
        for (int j = 0; j < 4; j++) {
            int flat = j * 256 + tid;
            int n = flat >> 3;
            int c8 = (flat & 7) << 3;
            *(short8*)&Bh[n * LDA + c8] = *(const short8*)(Whi + (size_t)n * IN_DIM + k0 + c8);
            *(short8*)&Bl[n * LDA + c8] = *(const short8*)(Wlo + (size_t)n * IN_DIM + k0 + c8);
        }
        __syncthreads();
#pragma unroll
        for (int ks = 0; ks < 2; ks++) {
            int kk = ks * 32 + koff;
            short8 ah[3], al[3], bh[4], bl[4];
#pragma unroll
            for (int s = 0; s < 3; s++) {
                int row = mh * 48 + s * 16 + r;
                ah[s] = *(const short8*)&Ah[row * LDA + kk];
                al[s] = *(const short8*)&Al[row * LDA + kk];
            }
#pragma unroll
            for (int nt = 0; nt < 4; nt++) {
                int n = q * 64 + nt * 16 + r;
                bh[nt] = *(const short8*)&Bh[n * LDA + kk];
                bl[nt] = *(const short8*)&Bl[n * LDA + kk];
            }
#pragma unroll
            for (int s = 0; s < 3; s++)
#pragma unroll
                for (int nt = 0; nt < 4; nt++) {
                    acc[s][nt] = __builtin_amdgcn_mfma_f32_16x16x32_bf16(ah[s], bh[nt], acc[s][nt], 0, 0, 0);
                    acc[s][nt] = __builtin_amdgcn_mfma_f32_16x16x32_bf16(al[s], bh[nt], acc[s][nt], 0, 0, 0);
                    acc[s][nt] = __builtin_amdgcn_mfma_f32_16x16x32_bf16(ah[s], bl[nt], acc[s][nt], 0, 0, 0);
                }
        }
    }
#pragma unroll
    for (int s = 0; s < 3; s++)
        epi(acc[s], m0 + mh * 48 + s * 16, q, lane, bias, attn, Zb, sS, sD);
}

// ------- FC2: LDS-tiled. A = h1 (single bf16 plane), W2 hi/lo. ----

__launch_bounds__(256)
__global__ void gemm_fc2(const unsigned short* __restrict__ Abf,
                         const unsigned short* __restrict__ Whi,
                         const unsigned short* __restrict__ Wlo,
                         const float* __restrict__ bias,
                         const float* __restrict__ attn,
                         unsigned short* __restrict__ Zb,
                         float* __restrict__ sS, float* __restrict__ sD) {
    __shared__ unsigned short Ah[TM * LDA];
    __shared__ unsigned short Bh[HID * LDA];
    __shared__ unsigned short Bl[HID * LDA];

    int tid  = threadIdx.x;
    int lane = tid & 63;
    int w    = tid >> 6;
    int q    = w & 1;
    int mh   = w >> 1;
    int m0   = blockIdx.x * TM;
    int r    = lane & 15;
    int koff = (lane >> 4) * 8;

    f32x4 acc[3][4];
#pragma unroll
    for (int s = 0; s < 3; s++)
#pragma unroll
        for (int nt = 0; nt < 4; nt++) acc[s][nt] = (f32x4){0.f, 0.f, 0.f, 0.f};

    for (int kc = 0; kc < HID / 64; kc++) {
        int k0 = kc * 64;
        __syncthreads();
#pragma unroll
        for (int j = 0; j < 3; j++) {
            int flat = j * 256 + tid;
            int row = flat >> 3;
            int c8 = (flat & 7) << 3;
            int gr = m0 + row;
            if (gr >= N_NODES) gr = N_NODES - 1;
            *(short8*)&Ah[row * LDA + c8] = *(const short8*)(Abf + (size_t)gr * HID + k0 + c8);
        }
#pragma unroll
        for (int j = 0; j < 4; j++) {
            int flat = j * 256 + tid;
            int n = flat >> 3;
            int c8 = (flat & 7) << 3;
            *(short8*)&Bh[n * LDA + c8] = *(const short8*)(Whi + (size_t)n * HID + k0 + c8);
            *(short8*)&Bl[n * LDA + c8] = *(const short8*)(Wlo + (size_t)n * HID + k0 + c8);
        }
        __syncthreads();
#pragma unroll
        for (int ks = 0; ks < 2; ks++) {
            int kk = ks * 32 + koff;
            short8 ah[3], bh[4], bl[4];
#pragma unroll
            for (int s = 0; s < 3; s++) {
                int row = mh * 48 + s * 16 + r;
                ah[s] = *(const short8*)&Ah[row * LDA + kk];
            }
#pragma unroll
            for (int nt = 0; nt < 4; nt++) {
                int n = q * 64 + nt * 16 + r;
                bh[nt] = *(const short8*)&Bh[n * LDA + kk];
                bl[nt] = *(const short8*)&Bl[n * LDA + kk];
            }
#pragma unroll
            for (int s = 0; s < 3; s++)
#pragma unroll
                for (int nt = 0; nt < 4; nt++) {
                    acc[s][nt] = __builtin_amdgcn_mfma_f32_16x16x32_bf16(ah[s], bh[nt], acc[s][nt], 0, 0, 0);
                    acc[s][nt] = __builtin_amdgcn_mfma_f32_16x16x32_bf16(ah[s], bl[nt], acc[s][nt], 0, 0, 0);
                }
        }
    }
#pragma unroll
    for (int s = 0; s < 3; s++)
        epi(acc[s], m0 + mh * 48 + s * 16, q, lane, bias, attn, Zb, sS, sD);
}

// ---------------- segment softmax + weighted gather-sum + ELU ----------------

template <int OUT_BF>
__launch_bounds__(256)
__global__ void aggregate(const unsigned short* __restrict__ Zb,
                          const int* __restrict__ csr_src,
                          const int* __restrict__ offsets,
                          const float* __restrict__ sS,
                          const float* __restrict__ sD,
                          const float* __restrict__ ab,
                          unsigned short* __restrict__ OutBf,
                          float* __restrict__ OutF) {
    int v = blockIdx.x * 4 + (threadIdx.x >> 6);
    int lane = threadIdx.x & 63;
    int off = offsets[v];
    int deg = offsets[v + 1] - off;
    float sdv = sD[v] + sD[v + N_NODES] + ab[0];

    const unsigned int* Zrow = (const unsigned int*)Zb;  // dword = 2 bf16 dims
    float2 acc = {0.f, 0.f};

    if (deg <= 64) {
        bool act = lane < deg;
        int s_l = 0;
        float x = -3.0e38f;
        if (act) {
            s_l = csr_src[off + lane];
            x = lky(sS[s_l] + sS[s_l + N_NODES] + sdv);
        }
        float mx = x;
#pragma unroll
        for (int o = 32; o > 0; o >>= 1) mx = fmaxf(mx, __shfl_xor(mx, o, 64));
        float ex = act ? __expf(x - mx) : 0.f;
        float sum = ex;
#pragma unroll
        for (int o = 32; o > 0; o >>= 1) sum += __shfl_xor(sum, o, 64);
        float al_l = (deg > 0) ? ex / sum : 0.f;

        int t = 0;
        for (; t + 8 <= deg; t += 8) {
            int   s[8];
            float a[8];
            unsigned int rw[8];
#pragma unroll
            for (int j = 0; j < 8; j++) {
                s[j] = __shfl(s_l, t + j, 64);
                a[j] = __shfl(al_l, t + j, 64);
            }
#pragma unroll
            for (int j = 0; j < 8; j++)
                rw[j] = Zrow[(size_t)s[j] * (HID / 2) + lane];
#pragma unroll
            for (int j = 0; j < 8; j++) {
                float2 zz = bfu2(rw[j]);
                acc.x += a[j] * zz.x;
                acc.y += a[j] * zz.y;
            }
        }
        for (; t < deg; t++) {
            int sj = __shfl(s_l, t, 64);
            float aj = __shfl(al_l, t, 64);
            float2 zz = bfu2(Zrow[(size_t)sj * (HID / 2) + lane]);
            acc.x += aj * zz.x;
            acc.y += aj * zz.y;
        }
    } else {
        float mx = -3.0e38f;
        for (int t = lane; t < deg; t += 64) {
            int s = csr_src[off + t];
            mx = fmaxf(mx, lky(sS[s] + sS[s + N_NODES] + sdv));
        }
#pragma unroll
        for (int o = 32; o > 0; o >>= 1) mx = fmaxf(mx, __shfl_xor(mx, o, 64));
        float sum = 0.f;
        for (int t = lane; t < deg; t += 64) {
            int s = csr_src[off + t];
            sum += __expf(lky(sS[s] + sS[s + N_NODES] + sdv) - mx);
        }
#pragma unroll
        for (int o = 32; o > 0; o >>= 1) sum += __shfl_xor(sum, o, 64);
        float inv = 1.f / sum;
        for (int t = 0; t < deg; t++) {
            int s = csr_src[off + t];
            float al = __expf(lky(sS[s] + sS[s + N_NODES] + sdv) - mx) * inv;
            float2 zz = bfu2(Zrow[(size_t)s * (HID / 2) + lane]);
            acc.x += al * zz.x;
            acc.y += al * zz.y;
        }
    }

    acc.x = acc.x > 0.f ? acc.x : __expf(acc.x) - 1.f;
    acc.y = acc.y > 0.f ? acc.y : __expf(acc.y) - 1.f;

    if (OUT_BF) {
        ushort2 o2;
        o2.x = f2bf(acc.x);
        o2.y = f2bf(acc.y);
        *((ushort2*)(OutBf + (size_t)v * HID + lane * 2)) = o2;
    } else {
        float2 o2 = {acc.x, acc.y};
        *((float2*)(OutF + (size_t)v * HID + lane * 2)) = o2;
    }
}

// ---------------- launch ----------------

extern "C" void kernel_launch(void* const* d_in, const int* in_sizes, int n_in,
                              void* d_out, int out_size, void* d_ws, size_t ws_size,
                              hipStream_t stream) {
    const float* h   = (const float*)d_in[0];
    const int*   src = (const int*)d_in[1];
    const int*   dst = (const int*)d_in[2];
    const float* W1  = (const float*)d_in[3];
    const float* b1  = (const float*)d_in[4];
    const float* a1  = (const float*)d_in[5];
    const float* ab1 = (const float*)d_in[6];
    const float* W2  = (const float*)d_in[7];
    const float* b2  = (const float*)d_in[8];
    const float* a2  = (const float*)d_in[9];
    const float* ab2 = (const float*)d_in[10];
    float* out = (float*)d_out;

    // workspace carve-up (~34 MB)
    unsigned short* zb = (unsigned short*)d_ws;                 // 50000*128 bf16
    float* sS = (float*)(zb + (size_t)N_NODES * HID);           // 2*50000 f32 (q-planes)
    float* sD = sS + 2 * N_NODES;                               // 2*50000 f32
    int* counts  = (int*)(sD + 2 * N_NODES);                    // 50000
    int* offsets = counts + N_NODES;                            // 50001 (+pad)
    int* bsums   = offsets + N_NODES + 16;                      // 256
    unsigned short* h1   = (unsigned short*)(bsums + 256);      // 50000*128 bf16
    unsigned short* w1hi = h1 + (size_t)N_NODES * HID;          // 32768
    unsigned short* w1lo = w1hi + W1_ELEMS;
    unsigned short* w2hi = w1lo + W1_ELEMS;                     // 16384
    unsigned short* w2lo = w2hi + W2_ELEMS;
    int* csr_src = (int*)(w2lo + W2_ELEMS);                     // 800000
    int* erank   = csr_src + N_EDGES;                           // 800000

    hipMemsetAsync(counts, 0, (size_t)N_NODES * sizeof(int), stream);

    // CSR by dst + weight splits; hist returns each edge's in-bucket rank
    hist_split<<<EDGE_BLOCKS, 256, 0, stream>>>(dst, counts, erank,
                                                W1, w1hi, w1lo, W2, w2hi, w2lo);
    scan_block<<<SCAN_BLOCKS, 256, 0, stream>>>(counts, offsets, bsums);
    scan_add<<<SCAN_BLOCKS, 256, 0, stream>>>(offsets, bsums);
    fill_kernel<<<EDGE_BLOCKS, 256, 0, stream>>>(dst, src, erank, offsets, csr_src);

    // layer 1
    gemm_fc1<<<FC_BLOCKS, 256, 0, stream>>>(h, w1hi, w1lo, b1, a1, zb, sS, sD);
    aggregate<1><<<NODE_WBLKS, 256, 0, stream>>>(zb, csr_src, offsets, sS, sD, ab1, h1, nullptr);

    // layer 2
    gemm_fc2<<<FC_BLOCKS, 256, 0, stream>>>(h1, w2hi, w2lo, b2, a2, zb, sS, sD);
    aggregate<0><<<NODE_WBLKS, 256, 0, stream>>>(zb, csr_src, offsets, sS, sD, ab2, nullptr, out);
}

// Round 9
// 282.299 us; speedup vs baseline: 1.2085x; 1.0278x over previous
//
#include <hip/hip_runtime.h>
#include <hip/hip_bf16.h>

#define N_NODES 50000
#define N_EDGES 800000
#define IN_DIM  256
#define HID     128
#define LEAKY   0.01f

#define EDGE_BLOCKS  ((N_EDGES + 255) / 256)      // 3125
#define NODE_WBLKS   (N_NODES / 4)                // 12500
#define SCAN_BLOCKS  ((N_NODES + 255) / 256)      // 196
#define W1_ELEMS  (HID * IN_DIM)                  // 32768
#define W2_ELEMS  (HID * HID)                     // 16384

#define TM        96                              // GEMM rows per block
#define FC_BLOCKS ((N_NODES + TM - 1) / TM)       // 521
#define LDA       72                              // LDS row stride (shorts)

typedef __attribute__((ext_vector_type(8))) short short8;
typedef __attribute__((ext_vector_type(4))) float f32x4;

__device__ __forceinline__ unsigned short f2bf(float x) {
    union { __hip_bfloat16 b; unsigned short u; } c;
    c.b = __float2bfloat16(x);
    return c.u;
}
__device__ __forceinline__ float bf2f(unsigned short u) {
    union { unsigned int u; float f; } c;
    c.u = ((unsigned int)u) << 16;
    return c.f;
}
__device__ __forceinline__ float2 bfu2(unsigned int u) {
    float2 r;
    r.x = bf2f((unsigned short)(u & 0xffff));
    r.y = bf2f((unsigned short)(u >> 16));
    return r;
}
__device__ __forceinline__ float lky(float x) { return x > 0.f ? x : LEAKY * x; }
__device__ __forceinline__ float rl_f(float v, int l) {
    return __int_as_float(__builtin_amdgcn_readlane(__float_as_int(v), l));
}

// ------- CSR hist (rank-returning) + W splits (fused, independent work) --------

__global__ void hist_split(const int* __restrict__ dst, int* __restrict__ counts,
                           int* __restrict__ erank,
                           const float* __restrict__ W1, unsigned short* __restrict__ w1hi,
                           unsigned short* __restrict__ w1lo,
                           const float* __restrict__ W2, unsigned short* __restrict__ w2hi,
                           unsigned short* __restrict__ w2lo) {
    int i = blockIdx.x * 256 + threadIdx.x;
    if (i < N_EDGES) erank[i] = atomicAdd(&counts[dst[i]], 1);
    if (i < W1_ELEMS) {
        float x = W1[i];
        unsigned short h = f2bf(x);
        w1hi[i] = h;
        w1lo[i] = f2bf(x - bf2f(h));
    } else if (i < W1_ELEMS + W2_ELEMS) {
        int j = i - W1_ELEMS;
        float x = W2[j];
        unsigned short h = f2bf(x);
        w2hi[j] = h;
        w2lo[j] = f2bf(x - bf2f(h));
    }
}

__global__ void scan_block(const int* __restrict__ counts, int* __restrict__ offsets,
                           int* __restrict__ bsums) {
    __shared__ int sh[256];
    int tid = threadIdx.x;
    int i = blockIdx.x * 256 + tid;
    int v = (i < N_NODES) ? counts[i] : 0;
    sh[tid] = v;
    __syncthreads();
    for (int o = 1; o < 256; o <<= 1) {
        int t = (tid >= o) ? sh[tid - o] : 0;
        __syncthreads();
        sh[tid] += t;
        __syncthreads();
    }
    if (i < N_NODES) offsets[i] = sh[tid] - v;
    if (tid == 255) bsums[blockIdx.x] = sh[255];
}

__global__ void scan_add(int* __restrict__ offsets, const int* __restrict__ bsums) {
    __shared__ int sh[256];
    int tid = threadIdx.x;
    int b = blockIdx.x;
    sh[tid] = (tid < b) ? bsums[tid] : 0;   // b <= 195 < 256
    __syncthreads();
    for (int o = 128; o > 0; o >>= 1) {
        if (tid < o) sh[tid] += sh[tid + o];
        __syncthreads();
    }
    int base = sh[0];
    int i = b * 256 + tid;
    if (i < N_NODES) offsets[i] += base;
    if (i == N_NODES) offsets[N_NODES] = N_EDGES;
}

// fill: atomic-free scatter; nontemporal store avoids cross-XCD L2 line bounce
__global__ void fill_kernel(const int* __restrict__ dst, const int* __restrict__ src,
                            const int* __restrict__ erank,
                            const int* __restrict__ offsets,
                            int* __restrict__ csr_src) {
    int i = blockIdx.x * 256 + threadIdx.x;
    if (i < N_EDGES) {
        int d = dst[i];
        int slot = offsets[d] + erank[i];
        __builtin_nontemporal_store(src[i], &csr_src[slot]);
    }
}

// ---------------- epilogue for one 16-row subtile ----------------
// C/D: col = lane&15, row = (lane>>4)*4 + reg. Partial scores reduce over r
// via shfl_xor, then land in LDS sbuf[q*192 + {0:S,96:D} + lrow] for block-combine.

__device__ __forceinline__ void epi(const f32x4* accn, int lrow0, int m0, int q, int lane,
                                    const float* __restrict__ bias,
                                    const float* __restrict__ attn,
                                    unsigned short* __restrict__ Zb,
                                    float* __restrict__ sbuf) {
    int r = lane & 15;
    int lrowbase = lrow0 + (lane >> 4) * 4;   // 0..95 within block
    float ps[4] = {0.f, 0.f, 0.f, 0.f};
    float pd[4] = {0.f, 0.f, 0.f, 0.f};
#pragma unroll
    for (int nt = 0; nt < 4; nt++) {
        int n = q * 64 + nt * 16 + r;
        float bn = bias[n];
        float aS = attn[n];
        float aD = attn[HID + n];
#pragma unroll
        for (int reg = 0; reg < 4; reg++) {
            float zv = accn[nt][reg] + bn;
            if (m0 + lrowbase + reg < N_NODES)
                Zb[(size_t)(m0 + lrowbase + reg) * HID + n] = f2bf(zv);
            ps[reg] += zv * aS;
            pd[reg] += zv * aD;
        }
    }
#pragma unroll
    for (int o = 1; o < 16; o <<= 1) {
#pragma unroll
        for (int reg = 0; reg < 4; reg++) {
            ps[reg] += __shfl_xor(ps[reg], o, 64);
            pd[reg] += __shfl_xor(pd[reg], o, 64);
        }
    }
    if (r == 0) {
#pragma unroll
        for (int reg = 0; reg < 4; reg++) {
            sbuf[q * 192 + lrowbase + reg] = ps[reg];
            sbuf[q * 192 + 96 + lrowbase + reg] = pd[reg];
        }
    }
}

// combine q-halves and store single score planes
__device__ __forceinline__ void score_combine(const float* __restrict__ sbuf, int tid, int m0,
                                              float* __restrict__ sS, float* __restrict__ sD) {
    if (tid < 96) {
        int gr = m0 + tid;
        if (gr < N_NODES) {
            sS[gr] = sbuf[tid] + sbuf[192 + tid];
            sD[gr] = sbuf[96 + tid] + sbuf[192 + 96 + tid];
        }
    }
}

// ------- FC1: LDS-tiled. Block = 96 rows x 128 cols, K in 64-elem chunks. -------

__launch_bounds__(256)
__global__ void gemm_fc1(const float* __restrict__ A,
                         const unsigned short* __restrict__ Whi,
                         const unsigned short* __restrict__ Wlo,
                         const float* __restrict__ bias,
                         const float* __restrict__ attn,
                         unsigned short* __restrict__ Zb,
                         float* __restrict__ sS, float* __restrict__ sD) {
    __shared__ unsigned short Ah[TM * LDA];
    __shared__ unsigned short Al[TM * LDA];
    __shared__ unsigned short Bh[HID * LDA];
    __shared__ unsigned short Bl[HID * LDA];

    int tid  = threadIdx.x;
    int lane = tid & 63;
    int w    = tid >> 6;
    int q    = w & 1;
    int mh   = w >> 1;
    int m0   = blockIdx.x * TM;
    int r    = lane & 15;
    int koff = (lane >> 4) * 8;

    f32x4 acc[3][4];
#pragma unroll
    for (int s = 0; s < 3; s++)
#pragma unroll
        for (int nt = 0; nt < 4; nt++) acc[s][nt] = (f32x4){0.f, 0.f, 0.f, 0.f};

    for (int kc = 0; kc < IN_DIM / 64; kc++) {
        int k0 = kc * 64;
        __syncthreads();
#pragma unroll
        for (int j = 0; j < 6; j++) {
            int flat = j * 256 + tid;
            int row = flat >> 4;
            int c4 = (flat & 15) << 2;
            int gr = m0 + row;
            if (gr >= N_NODES) gr = N_NODES - 1;
            float4 v = *(const float4*)(A + (size_t)gr * IN_DIM + k0 + c4);
            unsigned short h0 = f2bf(v.x), h1 = f2bf(v.y), h2 = f2bf(v.z), h3 = f2bf(v.w);
            short4 hv = {(short)h0, (short)h1, (short)h2, (short)h3};
            short4 lv = {(short)f2bf(v.x - bf2f(h0)), (short)f2bf(v.y - bf2f(h1)),
                         (short)f2bf(v.z - bf2f(h2)), (short)f2bf(v.w - bf2f(h3))};
            *(short4*)&Ah[row * LDA + c4] = hv;
            *(short4*)&Al[row * LDA + c4] = lv;
        }
#pragma unroll
        for (int j = 0; j < 4; j++) {
            int flat = j * 256 + tid;
            int n = flat >> 3;
            int c8 = (flat & 7) << 3;
            *(short8*)&Bh[n * LDA + c8] = *(const short8*)(Whi + (size_t)n * IN_DIM + k0 + c8);
            *(short8*)&Bl[n * LDA + c8] = *(const short8*)(Wlo + (size_t)n * IN_DIM + k0 + c8);
        }
        __syncthreads();
#pragma unroll
        for (int ks = 0; ks < 2; ks++) {
            int kk = ks * 32 + koff;
            short8 ah[3], al[3], bh[4], bl[4];
#pragma unroll
            for (int s = 0; s < 3; s++) {
                int row = mh * 48 + s * 16 + r;
                ah[s] = *(const short8*)&Ah[row * LDA + kk];
                al[s] = *(const short8*)&Al[row * LDA + kk];
            }
#pragma unroll
            for (int nt = 0; nt < 4; nt++) {
                int n = q * 64 + nt * 16 + r;
                bh[nt] = *(const short8*)&Bh[n * LDA + kk];
                bl[nt] = *(const short8*)&Bl[n * LDA + kk];
            }
#pragma unroll
            for (int s = 0; s < 3; s++)
#pragma unroll
                for (int nt = 0; nt < 4; nt++) {
                    acc[s][nt] = __builtin_amdgcn_mfma_f32_16x16x32_bf16(ah[s], bh[nt], acc[s][nt], 0, 0, 0);
                    acc[s][nt] = __builtin_amdgcn_mfma_f32_16x16x32_bf16(al[s], bh[nt], acc[s][nt], 0, 0, 0);
                    acc[s][nt] = __builtin_amdgcn_mfma_f32_16x16x32_bf16(ah[s], bl[nt], acc[s][nt], 0, 0, 0);
                }
        }
    }
    // ensure all LDS reads done, then reuse Ah as the score-exchange buffer
    __syncthreads();
    float* sbuf = (float*)Ah;   // 384 floats needed, Ah is 13824 B
#pragma unroll
    for (int s = 0; s < 3; s++)
        epi(acc[s], mh * 48 + s * 16, m0, q, lane, bias, attn, Zb, sbuf);
    __syncthreads();
    score_combine(sbuf, tid, m0, sS, sD);
}

// ------- FC2: LDS-tiled. A = h1 (single bf16 plane), W2 hi/lo. ----

__launch_bounds__(256)
__global__ void gemm_fc2(const unsigned short* __restrict__ Abf,
                         const unsigned short* __restrict__ Whi,
                         const unsigned short* __restrict__ Wlo,
                         const float* __restrict__ bias,
                         const float* __restrict__ attn,
                         unsigned short* __restrict__ Zb,
                         float* __restrict__ sS, float* __restrict__ sD) {
    __shared__ unsigned short Ah[TM * LDA];
    __shared__ unsigned short Bh[HID * LDA];
    __shared__ unsigned short Bl[HID * LDA];

    int tid  = threadIdx.x;
    int lane = tid & 63;
    int w    = tid >> 6;
    int q    = w & 1;
    int mh   = w >> 1;
    int m0   = blockIdx.x * TM;
    int r    = lane & 15;
    int koff = (lane >> 4) * 8;

    f32x4 acc[3][4];
#pragma unroll
    for (int s = 0; s < 3; s++)
#pragma unroll
        for (int nt = 0; nt < 4; nt++) acc[s][nt] = (f32x4){0.f, 0.f, 0.f, 0.f};

    for (int kc = 0; kc < HID / 64; kc++) {
        int k0 = kc * 64;
        __syncthreads();
#pragma unroll
        for (int j = 0; j < 3; j++) {
            int flat = j * 256 + tid;
            int row = flat >> 3;
            int c8 = (flat & 7) << 3;
            int gr = m0 + row;
            if (gr >= N_NODES) gr = N_NODES - 1;
            *(short8*)&Ah[row * LDA + c8] = *(const short8*)(Abf + (size_t)gr * HID + k0 + c8);
        }
#pragma unroll
        for (int j = 0; j < 4; j++) {
            int flat = j * 256 + tid;
            int n = flat >> 3;
            int c8 = (flat & 7) << 3;
            *(short8*)&Bh[n * LDA + c8] = *(const short8*)(Whi + (size_t)n * HID + k0 + c8);
            *(short8*)&Bl[n * LDA + c8] = *(const short8*)(Wlo + (size_t)n * HID + k0 + c8);
        }
        __syncthreads();
#pragma unroll
        for (int ks = 0; ks < 2; ks++) {
            int kk = ks * 32 + koff;
            short8 ah[3], bh[4], bl[4];
#pragma unroll
            for (int s = 0; s < 3; s++) {
                int row = mh * 48 + s * 16 + r;
                ah[s] = *(const short8*)&Ah[row * LDA + kk];
            }
#pragma unroll
            for (int nt = 0; nt < 4; nt++) {
                int n = q * 64 + nt * 16 + r;
                bh[nt] = *(const short8*)&Bh[n * LDA + kk];
                bl[nt] = *(const short8*)&Bl[n * LDA + kk];
            }
#pragma unroll
            for (int s = 0; s < 3; s++)
#pragma unroll
                for (int nt = 0; nt < 4; nt++) {
                    acc[s][nt] = __builtin_amdgcn_mfma_f32_16x16x32_bf16(ah[s], bh[nt], acc[s][nt], 0, 0, 0);
                    acc[s][nt] = __builtin_amdgcn_mfma_f32_16x16x32_bf16(ah[s], bl[nt], acc[s][nt], 0, 0, 0);
                }
        }
    }
    __syncthreads();
    float* sbuf = (float*)Ah;
#pragma unroll
    for (int s = 0; s < 3; s++)
        epi(acc[s], mh * 48 + s * 16, m0, q, lane, bias, attn, Zb, sbuf);
    __syncthreads();
    score_combine(sbuf, tid, m0, sS, sD);
}

// ---------------- segment softmax + weighted gather-sum + ELU ----------------
// one wave per dst node. Fast path: per-edge (src, alpha) in lane registers;
// phase C broadcasts via v_readlane (scalar pipe, no LDS), 16-deep MLP batches.

template <int OUT_BF>
__launch_bounds__(256)
__global__ void aggregate(const unsigned short* __restrict__ Zb,
                          const int* __restrict__ csr_src,
                          const int* __restrict__ offsets,
                          const float* __restrict__ sS,
                          const float* __restrict__ sD,
                          const float* __restrict__ ab,
                          unsigned short* __restrict__ OutBf,
                          float* __restrict__ OutF) {
    int v = blockIdx.x * 4 + (threadIdx.x >> 6);
    int lane = threadIdx.x & 63;
    int off = offsets[v];
    int deg = offsets[v + 1] - off;
    float sdv = sD[v] + ab[0];

    const unsigned int* Zrow = (const unsigned int*)Zb;  // dword = 2 bf16 dims
    float2 acc = {0.f, 0.f};

    if (deg <= 64) {
        bool act = lane < deg;
        int s_l = 0;
        float x = -3.0e38f;
        if (act) {
            s_l = csr_src[off + lane];
            x = lky(sS[s_l] + sdv);
        }
        float mx = x;
#pragma unroll
        for (int o = 32; o > 0; o >>= 1) mx = fmaxf(mx, __shfl_xor(mx, o, 64));
        float ex = act ? __expf(x - mx) : 0.f;
        float sum = ex;
#pragma unroll
        for (int o = 32; o > 0; o >>= 1) sum += __shfl_xor(sum, o, 64);
        float al_l = (deg > 0) ? ex / sum : 0.f;

        int t = 0;
        for (; t + 16 <= deg; t += 16) {
            int   s[16];
            float a[16];
            unsigned int rw[16];
#pragma unroll
            for (int j = 0; j < 16; j++) {
                s[j] = __builtin_amdgcn_readlane(s_l, t + j);
                a[j] = rl_f(al_l, t + j);
            }
#pragma unroll
            for (int j = 0; j < 16; j++)
                rw[j] = Zrow[(size_t)s[j] * (HID / 2) + lane];
#pragma unroll
            for (int j = 0; j < 16; j++) {
                float2 zz = bfu2(rw[j]);
                acc.x += a[j] * zz.x;
                acc.y += a[j] * zz.y;
            }
        }
        for (; t + 4 <= deg; t += 4) {
            int   s[4];
            float a[4];
            unsigned int rw[4];
#pragma unroll
            for (int j = 0; j < 4; j++) {
                s[j] = __builtin_amdgcn_readlane(s_l, t + j);
                a[j] = rl_f(al_l, t + j);
            }
#pragma unroll
            for (int j = 0; j < 4; j++)
                rw[j] = Zrow[(size_t)s[j] * (HID / 2) + lane];
#pragma unroll
            for (int j = 0; j < 4; j++) {
                float2 zz = bfu2(rw[j]);
                acc.x += a[j] * zz.x;
                acc.y += a[j] * zz.y;
            }
        }
        for (; t < deg; t++) {
            int sj = __builtin_amdgcn_readlane(s_l, t);
            float aj = rl_f(al_l, t);
            float2 zz = bfu2(Zrow[(size_t)sj * (HID / 2) + lane]);
            acc.x += aj * zz.x;
            acc.y += aj * zz.y;
        }
    } else {
        float mx = -3.0e38f;
        for (int t = lane; t < deg; t += 64) {
            int s = csr_src[off + t];
            mx = fmaxf(mx, lky(sS[s] + sdv));
        }
#pragma unroll
        for (int o = 32; o > 0; o >>= 1) mx = fmaxf(mx, __shfl_xor(mx, o, 64));
        float sum = 0.f;
        for (int t = lane; t < deg; t += 64) {
            int s = csr_src[off + t];
            sum += __expf(lky(sS[s] + sdv) - mx);
        }
#pragma unroll
        for (int o = 32; o > 0; o >>= 1) sum += __shfl_xor(sum, o, 64);
        float inv = 1.f / sum;
        for (int t = 0; t < deg; t++) {
            int s = csr_src[off + t];
            float al = __expf(lky(sS[s] + sdv) - mx) * inv;
            float2 zz = bfu2(Zrow[(size_t)s * (HID / 2) + lane]);
            acc.x += al * zz.x;
            acc.y += al * zz.y;
        }
    }

    acc.x = acc.x > 0.f ? acc.x : __expf(acc.x) - 1.f;
    acc.y = acc.y > 0.f ? acc.y : __expf(acc.y) - 1.f;

    if (OUT_BF) {
        ushort2 o2;
        o2.x = f2bf(acc.x);
        o2.y = f2bf(acc.y);
        *((ushort2*)(OutBf + (size_t)v * HID + lane * 2)) = o2;
    } else {
        float2 o2 = {acc.x, acc.y};
        *((float2*)(OutF + (size_t)v * HID + lane * 2)) = o2;
    }
}

// ---------------- launch ----------------

extern "C" void kernel_launch(void* const* d_in, const int* in_sizes, int n_in,
                              void* d_out, int out_size, void* d_ws, size_t ws_size,
                              hipStream_t stream) {
    const float* h   = (const float*)d_in[0];
    const int*   src = (const int*)d_in[1];
    const int*   dst = (const int*)d_in[2];
    const float* W1  = (const float*)d_in[3];
    const float* b1  = (const float*)d_in[4];
    const float* a1  = (const float*)d_in[5];
    const float* ab1 = (const float*)d_in[6];
    const float* W2  = (const float*)d_in[7];
    const float* b2  = (const float*)d_in[8];
    const float* a2  = (const float*)d_in[9];
    const float* ab2 = (const float*)d_in[10];
    float* out = (float*)d_out;

    // workspace carve-up (~34 MB)
    unsigned short* zb = (unsigned short*)d_ws;                 // 50000*128 bf16
    float* sS = (float*)(zb + (size_t)N_NODES * HID);           // 50000 f32
    float* sD = sS + N_NODES;                                   // 50000 f32
    int* counts  = (int*)(sD + N_NODES);                        // 50000
    int* offsets = counts + N_NODES;                            // 50001 (+pad)
    int* bsums   = offsets + N_NODES + 16;                      // 256
    unsigned short* h1   = (unsigned short*)(bsums + 256);      // 50000*128 bf16
    unsigned short* w1hi = h1 + (size_t)N_NODES * HID;          // 32768
    unsigned short* w1lo = w1hi + W1_ELEMS;
    unsigned short* w2hi = w1lo + W1_ELEMS;                     // 16384
    unsigned short* w2lo = w2hi + W2_ELEMS;
    int* csr_src = (int*)(w2lo + W2_ELEMS);                     // 800000
    int* erank   = csr_src + N_EDGES;                           // 800000

    hipMemsetAsync(counts, 0, (size_t)N_NODES * sizeof(int), stream);

    // CSR by dst + weight splits; hist returns each edge's in-bucket rank
    hist_split<<<EDGE_BLOCKS, 256, 0, stream>>>(dst, counts, erank,
                                                W1, w1hi, w1lo, W2, w2hi, w2lo);
    scan_block<<<SCAN_BLOCKS, 256, 0, stream>>>(counts, offsets, bsums);
    scan_add<<<SCAN_BLOCKS, 256, 0, stream>>>(offsets, bsums);
    fill_kernel<<<EDGE_BLOCKS, 256, 0, stream>>>(dst, src, erank, offsets, csr_src);

    // layer 1
    gemm_fc1<<<FC_BLOCKS, 256, 0, stream>>>(h, w1hi, w1lo, b1, a1, zb, sS, sD);
    aggregate<1><<<NODE_WBLKS, 256, 0, stream>>>(zb, csr_src, offsets, sS, sD, ab1, h1, nullptr);

    // layer 2
    gemm_fc2<<<FC_BLOCKS, 256, 0, stream>>>(h1, w2hi, w2lo, b2, a2, zb, sS, sD);
    aggregate<0><<<NODE_WBLKS, 256, 0, stream>>>(zb, csr_src, offsets, sS, sD, ab2, nullptr, out);
}